// Round 5
// baseline (382.333 us; speedup 1.0000x reference)
//
#include <hip/hip_runtime.h>

#define EPSF 1e-8f

typedef __fp16   h2v   __attribute__((ext_vector_type(2)));
typedef _Float16 half8 __attribute__((ext_vector_type(8)));
typedef float    f32x16 __attribute__((ext_vector_type(16)));

constexpr int Bn = 64, Cc = 768, Nn = 1024, Mm = 100;

__device__ inline f32x16 zero16() {
    f32x16 z;
#pragma unroll
    for (int i = 0; i < 16; ++i) z[i] = 0.f;
    return z;
}

union U4H8 { uint4 u; half8 h; h2v p[4]; };

__device__ inline unsigned pkr(float a, float b) {
    union { h2v p; unsigned u; } cv;
    cv.p = __builtin_amdgcn_cvt_pkrtz(a, b);
    return cv.u;
}

// Fragment-major prep (unchanged from round 4).
// GEMM1 A (normalized mem, hi/lo f16):  idx = ((cs*4 + mt)*64 + hb*32 + ml)*8 + j
// GEMM2 A (raw mem, transposed):        idx = ((ct*8 + ms)*64 + hm*32 + cl)*8 + jm
__global__ __launch_bounds__(256) void prep_kernel(const float* __restrict__ mem,
                                                   _Float16* __restrict__ mhiF,
                                                   _Float16* __restrict__ mloF,
                                                   _Float16* __restrict__ muF) {
    int m = blockIdx.x, t = threadIdx.x;
    float inv = 0.f;
    if (m < Mm) {
        float ss = 0.f;
        for (int c = t; c < Cc; c += 256) { float v = mem[m * Cc + c]; ss += v * v; }
        __shared__ float red[256];
        red[t] = ss; __syncthreads();
        for (int s = 128; s > 0; s >>= 1) { if (t < s) red[t] += red[t + s]; __syncthreads(); }
        inv = 1.f / fmaxf(sqrtf(red[0]), 1e-12f);
    }
    for (int c = t; c < Cc; c += 256) {
        float v = (m < Mm) ? mem[m * Cc + c] : 0.f;
        float nv = v * inv;
        _Float16 hh = (_Float16)nv;
        _Float16 ll = (_Float16)(nv - (float)hh);
        int cs = c >> 4, hb = (c >> 3) & 1, j = c & 7, mt = m >> 5, ml = m & 31;
        size_t idx = ((size_t)(cs * 4 + mt) * 64 + hb * 32 + ml) * 8 + j;
        mhiF[idx] = hh;
        mloF[idx] = ll;
        int ct = c >> 5, cl = c & 31, ms = m >> 4, hm = (m >> 3) & 1, jm = m & 7;
        size_t idx2 = ((size_t)(ct * 8 + ms) * 64 + hm * 32 + cl) * 8 + jm;
        muF[idx2] = (_Float16)v;
    }
}

// Block = 2 waves sharing one 32-px group. Wave w does K-half w in GEMM1 and
// c-half w in GEMM2. 2048 blocks x 128 thr -> 4096 waves = 16/CU.
__global__ __launch_bounds__(128, 4) void fused_mem_kernel(
    const float* __restrict__ z, const _Float16* __restrict__ mhiF,
    const _Float16* __restrict__ mloF, const _Float16* __restrict__ muF,
    float* __restrict__ zhat, float* __restrict__ attn_out) {
    __shared__ float sx[4][16][64];   // 16 KB: score exchange, later bfr exchange
    __shared__ float r2x[4][2][32];   // 1 KB: ss / max / sum / asum exchanges

    const int tid = threadIdx.x;
    const int w = tid >> 6;           // wave in block: 0 or 1
    const int l = tid & 63;
    const int gb = blockIdx.x;        // 0..2047, one 32-px group each
    const int b = gb >> 5;
    const int pxb = (gb & 31) * 32;
    const int pl = l & 31;
    const int h = l >> 5;
    const float* zp = z + (size_t)b * Cc * Nn + pxb + pl;
    const float* zr = zp + (size_t)(w * 384 + h * 8) * Nn;
    const uint4* mh4 = (const uint4*)mhiF;
    const uint4* ml4 = (const uint4*)mloF;
    const int cs0 = w * 24;

    // ---------------- GEMM1 (K-half): partial scoresT ----------------
    f32x16 acc[4] = {zero16(), zero16(), zero16(), zero16()};
    float ss = 0.f;
    float zc[8], zn[8];
    uint4 fh[4], fl_[4], fh2[4], fl2[4];
#pragma unroll
    for (int j = 0; j < 8; ++j) zc[j] = zr[(size_t)j * Nn];
#pragma unroll
    for (int mt = 0; mt < 4; ++mt) {
        fh[mt] = mh4[(cs0 * 4 + mt) * 64 + l];
        fl_[mt] = ml4[(cs0 * 4 + mt) * 64 + l];
    }

#pragma unroll 2
    for (int csl = 0; csl < 24; ++csl) {
        if (csl < 23) {  // prefetch next K-step
#pragma unroll
            for (int j = 0; j < 8; ++j) zn[j] = zr[(size_t)((csl + 1) * 16 + j) * Nn];
#pragma unroll
            for (int mt = 0; mt < 4; ++mt) {
                fh2[mt] = mh4[((cs0 + csl + 1) * 4 + mt) * 64 + l];
                fl2[mt] = ml4[((cs0 + csl + 1) * 4 + mt) * 64 + l];
            }
        }
        U4H8 zh, zl8;
#pragma unroll
        for (int t = 0; t < 4; ++t) {
            float u = zc[2 * t], v = zc[2 * t + 1];
            h2v p = __builtin_amdgcn_cvt_pkrtz(u, v);
            zh.p[t] = p;
            zl8.p[t] = __builtin_amdgcn_cvt_pkrtz(u - (float)p.x, v - (float)p.y);
            ss += u * u + v * v;
        }
#pragma unroll
        for (int mt = 0; mt < 4; ++mt) {
            U4H8 ah, al;
            ah.u = fh[mt]; al.u = fl_[mt];
            acc[mt] = __builtin_amdgcn_mfma_f32_32x32x16_f16(ah.h, zh.h, acc[mt], 0, 0, 0);
            acc[mt] = __builtin_amdgcn_mfma_f32_32x32x16_f16(al.h, zh.h, acc[mt], 0, 0, 0);
            acc[mt] = __builtin_amdgcn_mfma_f32_32x32x16_f16(ah.h, zl8.h, acc[mt], 0, 0, 0);
        }
#pragma unroll
        for (int j = 0; j < 8; ++j) zc[j] = zn[j];
#pragma unroll
        for (int mt = 0; mt < 4; ++mt) { fh[mt] = fh2[mt]; fl_[mt] = fl2[mt]; }
    }

    // ---------------- cross-wave score + norm exchange ----------------
    ss += __shfl_xor(ss, 32);
    if (h == 0) r2x[0][w][pl] = ss;
    // wave w writes its NON-owned tiles (2*(1-w), 2*(1-w)+1) into slots 2w, 2w+1
#pragma unroll
    for (int i = 0; i < 2; ++i)
#pragma unroll
        for (int r = 0; r < 16; ++r) sx[2 * w + i][r][l] = acc[2 * (1 - w) + i][r];
    __syncthreads();
#pragma unroll
    for (int i = 0; i < 2; ++i)
#pragma unroll
        for (int r = 0; r < 16; ++r) acc[2 * w + i][r] += sx[2 * (1 - w) + i][r][l];
    float sst = r2x[0][0][pl] + r2x[0][1][pl];
    float invn = 1.f / fmaxf(sqrtf(sst), 1e-12f);

    // ---------------- split softmax + shrinkage (wave owns m-half 64w..64w+63) ----
    float a_[32];
#pragma unroll
    for (int t = 0; t < 2; ++t)
#pragma unroll
        for (int rr = 0; rr < 16; ++rr) {
            float v = acc[2 * w + t][rr] * invn;
            if (w == 1 && t == 1 && !(h == 0 && rr < 4)) v = -3.0e38f;  // m>=100 pad
            a_[t * 16 + rr] = v;
        }
    float mx = -3.0e38f;
#pragma unroll
    for (int r = 0; r < 32; ++r) mx = fmaxf(mx, a_[r]);
    mx = fmaxf(mx, __shfl_xor(mx, 32));
    if (h == 0) r2x[1][w][pl] = mx;
    __syncthreads();
    mx = fmaxf(r2x[1][0][pl], r2x[1][1][pl]);

    float sum = 0.f;
#pragma unroll
    for (int r = 0; r < 32; ++r) { float e = expf(a_[r] - mx); a_[r] = e; sum += e; }
    sum += __shfl_xor(sum, 32);
    if (h == 0) r2x[2][w][pl] = sum;
    __syncthreads();
    float itot = 1.f / (r2x[2][0][pl] + r2x[2][1][pl]);

    float asum = 0.f;
#pragma unroll
    for (int r = 0; r < 32; ++r) {
        float wgt = a_[r] * itot;
        float d = wgt - 0.01f;
        float aa = (d > 0.f) ? (d * wgt) / (d + EPSF) : 0.f;
        a_[r] = aa; asum += aa;
    }
    asum += __shfl_xor(asum, 32);
    if (h == 0) r2x[3][w][pl] = asum;
    __syncthreads();
    float ia = 1.f / (r2x[3][0][pl] + r2x[3][1][pl] + EPSF);
#pragma unroll
    for (int r = 0; r < 32; ++r) a_[r] *= ia;

    // ---- store attn (own m-half) ----
    {
        size_t ob = (size_t)(gb * 32 + pl) * (size_t)Mm;
#pragma unroll
        for (int g = 0; g < 8; ++g) {
            int r0 = g * 4;
            int m0 = 64 * w + (r0 >> 4) * 32 + 8 * ((r0 >> 2) & 3) + 4 * h;
            if (m0 < Mm) {
                float4 v = make_float4(a_[r0], a_[r0 + 1], a_[r0 + 2], a_[r0 + 3]);
                *(float4*)&attn_out[ob + m0] = v;
            }
        }
    }

    // ---- build + exchange GEMM2 B-fragments (attn f16, k=m) ----
    uint4 bloc[4];
#pragma unroll
    for (int t = 0; t < 2; ++t) {
        unsigned p0 = pkr(a_[16 * t + 0], a_[16 * t + 1]);
        unsigned p1 = pkr(a_[16 * t + 2], a_[16 * t + 3]);
        unsigned p2 = pkr(a_[16 * t + 4], a_[16 * t + 5]);
        unsigned p3 = pkr(a_[16 * t + 6], a_[16 * t + 7]);
        unsigned p4 = pkr(a_[16 * t + 8], a_[16 * t + 9]);
        unsigned p5 = pkr(a_[16 * t + 10], a_[16 * t + 11]);
        unsigned p6 = pkr(a_[16 * t + 12], a_[16 * t + 13]);
        unsigned p7 = pkr(a_[16 * t + 14], a_[16 * t + 15]);
        unsigned s0 = __shfl_xor(p0, 32), s1 = __shfl_xor(p1, 32);
        unsigned s2 = __shfl_xor(p2, 32), s3 = __shfl_xor(p3, 32);
        unsigned s4 = __shfl_xor(p4, 32), s5 = __shfl_xor(p5, 32);
        unsigned s6 = __shfl_xor(p6, 32), s7 = __shfl_xor(p7, 32);
        bloc[2 * t]     = h ? make_uint4(s2, s3, p2, p3) : make_uint4(p0, p1, s0, s1);
        bloc[2 * t + 1] = h ? make_uint4(s6, s7, p6, p7) : make_uint4(p4, p5, s4, s5);
    }
    uint4* bx = (uint4*)&sx[0][0][0];  // safe: all score reads done (asum barrier)
#pragma unroll
    for (int i = 0; i < 4; ++i) bx[(4 * w + i) * 64 + l] = bloc[i];
    __syncthreads();
    uint4 bfr[8];
#pragma unroll
    for (int i = 0; i < 4; ++i) {
        bfr[4 * w + i] = bloc[i];
        bfr[4 * (1 - w) + i] = bx[(4 * (1 - w) + i) * 64 + l];
    }

    // ---------------- GEMM2 (c-half): z_hat = memT . attn ----------------
    const uint4* mu4 = (const uint4*)muF;
    float* zo = zhat + (size_t)b * Cc * Nn + pxb + pl;
    const int ct0 = w * 12;
#pragma unroll 1
    for (int cti = 0; cti < 12; cti += 2) {
        int ct = ct0 + cti;
        f32x16 a2 = zero16(), a3 = zero16();
#pragma unroll
        for (int ms = 0; ms < 8; ++ms) {
            U4H8 A0, A1, Bf;
            A0.u = mu4[(ct * 8 + ms) * 64 + l];
            A1.u = mu4[((ct + 1) * 8 + ms) * 64 + l];
            Bf.u = bfr[ms];
            a2 = __builtin_amdgcn_mfma_f32_32x32x16_f16(A0.h, Bf.h, a2, 0, 0, 0);
            a3 = __builtin_amdgcn_mfma_f32_32x32x16_f16(A1.h, Bf.h, a3, 0, 0, 0);
        }
#pragma unroll
        for (int r = 0; r < 16; ++r) {
            int cl = (r & 3) + 8 * (r >> 2) + 4 * h;
            zo[(size_t)(ct * 32 + cl) * Nn] = a2[r];
            zo[(size_t)(ct * 32 + 32 + cl) * Nn] = a3[r];
        }
    }
}

extern "C" void kernel_launch(void* const* d_in, const int* in_sizes, int n_in,
                              void* d_out, int out_size, void* d_ws, size_t ws_size,
                              hipStream_t stream) {
    const float* z = (const float*)d_in[0];
    const float* mem = (const float*)d_in[1];
    float* out = (float*)d_out;
    float* zhat = out;                          // 64*768*1024
    float* attn = out + (size_t)Bn * Cc * Nn;   // 64*1024*100
    _Float16* mhiF = (_Float16*)d_ws;           // 192 KB
    _Float16* mloF = mhiF + 48 * 4 * 64 * 8;    // 192 KB
    _Float16* muF = mloF + 48 * 4 * 64 * 8;     // 192 KB

    prep_kernel<<<128, 256, 0, stream>>>(mem, mhiF, mloF, muF);
    fused_mem_kernel<<<2048, 128, 0, stream>>>(z, mhiF, mloF, muF, zhat, attn);
}

// Round 6
// 218.485 us; speedup vs baseline: 1.7499x; 1.7499x over previous
//
#include <hip/hip_runtime.h>

#define EPSF 1e-8f

typedef __fp16   h2v   __attribute__((ext_vector_type(2)));
typedef _Float16 half8 __attribute__((ext_vector_type(8)));
typedef float    f32x16 __attribute__((ext_vector_type(16)));

constexpr int Bn = 64, Cc = 768, Nn = 1024, Mm = 100;

__device__ inline f32x16 zero16() {
    f32x16 z;
#pragma unroll
    for (int i = 0; i < 16; ++i) z[i] = 0.f;
    return z;
}

union U4H8 { uint4 u; half8 h; h2v p[4]; };

__device__ inline unsigned pkr(float a, float b) {
    union { h2v p; unsigned u; } cv;
    cv.p = __builtin_amdgcn_cvt_pkrtz(a, b);
    return cv.u;
}

// Fragment-major prep (unchanged).
// GEMM1 A (normalized mem, hi/lo f16):  idx = ((cs*4 + mt)*64 + hb*32 + ml)*8 + j
// GEMM2 A (raw mem, transposed):        idx = ((ct*8 + ms)*64 + hm*32 + cl)*8 + jm
__global__ __launch_bounds__(256) void prep_kernel(const float* __restrict__ mem,
                                                   _Float16* __restrict__ mhiF,
                                                   _Float16* __restrict__ mloF,
                                                   _Float16* __restrict__ muF) {
    int m = blockIdx.x, t = threadIdx.x;
    float inv = 0.f;
    if (m < Mm) {
        float ss = 0.f;
        for (int c = t; c < Cc; c += 256) { float v = mem[m * Cc + c]; ss += v * v; }
        __shared__ float red[256];
        red[t] = ss; __syncthreads();
        for (int s = 128; s > 0; s >>= 1) { if (t < s) red[t] += red[t + s]; __syncthreads(); }
        inv = 1.f / fmaxf(sqrtf(red[0]), 1e-12f);
    }
    for (int c = t; c < Cc; c += 256) {
        float v = (m < Mm) ? mem[m * Cc + c] : 0.f;
        float nv = v * inv;
        _Float16 hh = (_Float16)nv;
        _Float16 ll = (_Float16)(nv - (float)hh);
        int cs = c >> 4, hb = (c >> 3) & 1, j = c & 7, mt = m >> 5, ml = m & 31;
        size_t idx = ((size_t)(cs * 4 + mt) * 64 + hb * 32 + ml) * 8 + j;
        mhiF[idx] = hh;
        mloF[idx] = ll;
        int ct = c >> 5, cl = c & 31, ms = m >> 4, hm = (m >> 3) & 1, jm = m & 7;
        size_t idx2 = ((size_t)(ct * 8 + ms) * 64 + hm * 32 + cl) * 8 + jm;
        muF[idx2] = (_Float16)v;
    }
}

// Block = 2 waves sharing one 32-px group. Wave w does K-half w in GEMM1 and
// c-half w in GEMM2. 2048 blocks x 128 thr -> 4096 waves.
// launch_bounds(128,3): VGPR cap ~170 -- live set ~120, no spill (round-5 bug).
__global__ __launch_bounds__(128, 3) void fused_mem_kernel(
    const float* __restrict__ z, const _Float16* __restrict__ mhiF,
    const _Float16* __restrict__ mloF, const _Float16* __restrict__ muF,
    float* __restrict__ zhat, float* __restrict__ attn_out) {
    __shared__ float sx[4][16][64];   // 16 KB: score exchange, later bfr exchange
    __shared__ float r2x[4][2][32];   // 1 KB: ss / max / sum / asum exchanges

    const int tid = threadIdx.x;
    const int w = tid >> 6;           // wave in block: 0 or 1
    const int l = tid & 63;
    const int gb = blockIdx.x;        // 0..2047, one 32-px group each
    const int b = gb >> 5;
    const int pxb = (gb & 31) * 32;
    const int pl = l & 31;
    const int h = l >> 5;
    const float* zp = z + (size_t)b * Cc * Nn + pxb + pl;
    const float* zr = zp + (size_t)(w * 384 + h * 8) * Nn;
    const uint4* mh4 = (const uint4*)mhiF;
    const uint4* ml4 = (const uint4*)mloF;
    const int cs0 = w * 24;

    // ---------------- GEMM1 (K-half): partial scoresT ----------------
    f32x16 acc[4] = {zero16(), zero16(), zero16(), zero16()};
    float ss = 0.f;
    float zc[8], zn[8];
#pragma unroll
    for (int j = 0; j < 8; ++j) zc[j] = zr[(size_t)j * Nn];

#pragma unroll 2
    for (int csl = 0; csl < 24; ++csl) {
        // fragment loads for this K-step (L2-resident; no double-buffer -> VGPR headroom)
        uint4 fh[4], fl_[4];
#pragma unroll
        for (int mt = 0; mt < 4; ++mt) {
            fh[mt] = mh4[((cs0 + csl) * 4 + mt) * 64 + l];
            fl_[mt] = ml4[((cs0 + csl) * 4 + mt) * 64 + l];
        }
        if (csl < 23) {  // prefetch next z K-step (HBM stream)
#pragma unroll
            for (int j = 0; j < 8; ++j) zn[j] = zr[(size_t)((csl + 1) * 16 + j) * Nn];
        }
        U4H8 zh, zl8;
#pragma unroll
        for (int t = 0; t < 4; ++t) {
            float u = zc[2 * t], v = zc[2 * t + 1];
            h2v p = __builtin_amdgcn_cvt_pkrtz(u, v);
            zh.p[t] = p;
            zl8.p[t] = __builtin_amdgcn_cvt_pkrtz(u - (float)p.x, v - (float)p.y);
            ss += u * u + v * v;
        }
#pragma unroll
        for (int mt = 0; mt < 4; ++mt) {
            U4H8 ah, al;
            ah.u = fh[mt]; al.u = fl_[mt];
            acc[mt] = __builtin_amdgcn_mfma_f32_32x32x16_f16(ah.h, zh.h, acc[mt], 0, 0, 0);
            acc[mt] = __builtin_amdgcn_mfma_f32_32x32x16_f16(al.h, zh.h, acc[mt], 0, 0, 0);
            acc[mt] = __builtin_amdgcn_mfma_f32_32x32x16_f16(ah.h, zl8.h, acc[mt], 0, 0, 0);
        }
#pragma unroll
        for (int j = 0; j < 8; ++j) zc[j] = zn[j];
    }

    // ---------------- cross-wave score + norm exchange ----------------
    ss += __shfl_xor(ss, 32);
    if (h == 0) r2x[0][w][pl] = ss;
    // wave w writes its NON-owned tiles (2*(1-w), 2*(1-w)+1) into slots 2w, 2w+1
#pragma unroll
    for (int i = 0; i < 2; ++i)
#pragma unroll
        for (int r = 0; r < 16; ++r) sx[2 * w + i][r][l] = acc[2 * (1 - w) + i][r];
    __syncthreads();
#pragma unroll
    for (int i = 0; i < 2; ++i)
#pragma unroll
        for (int r = 0; r < 16; ++r) acc[2 * w + i][r] += sx[2 * (1 - w) + i][r][l];
    float sst = r2x[0][0][pl] + r2x[0][1][pl];
    float invn = 1.f / fmaxf(sqrtf(sst), 1e-12f);

    // ---------------- split softmax + shrinkage (wave owns m-half 64w..64w+63) ----
    float a_[32];
#pragma unroll
    for (int t = 0; t < 2; ++t)
#pragma unroll
        for (int rr = 0; rr < 16; ++rr) {
            float v = acc[2 * w + t][rr] * invn;
            if (w == 1 && t == 1 && !(h == 0 && rr < 4)) v = -3.0e38f;  // m>=100 pad
            a_[t * 16 + rr] = v;
        }
    float mx = -3.0e38f;
#pragma unroll
    for (int r = 0; r < 32; ++r) mx = fmaxf(mx, a_[r]);
    mx = fmaxf(mx, __shfl_xor(mx, 32));
    if (h == 0) r2x[1][w][pl] = mx;
    __syncthreads();
    mx = fmaxf(r2x[1][0][pl], r2x[1][1][pl]);

    float sum = 0.f;
#pragma unroll
    for (int r = 0; r < 32; ++r) { float e = expf(a_[r] - mx); a_[r] = e; sum += e; }
    sum += __shfl_xor(sum, 32);
    if (h == 0) r2x[2][w][pl] = sum;
    __syncthreads();
    float itot = 1.f / (r2x[2][0][pl] + r2x[2][1][pl]);

    float asum = 0.f;
#pragma unroll
    for (int r = 0; r < 32; ++r) {
        float wgt = a_[r] * itot;
        float d = wgt - 0.01f;
        float aa = (d > 0.f) ? (d * wgt) / (d + EPSF) : 0.f;
        a_[r] = aa; asum += aa;
    }
    asum += __shfl_xor(asum, 32);
    if (h == 0) r2x[3][w][pl] = asum;
    __syncthreads();
    float ia = 1.f / (r2x[3][0][pl] + r2x[3][1][pl] + EPSF);
#pragma unroll
    for (int r = 0; r < 32; ++r) a_[r] *= ia;

    // ---- store attn (own m-half) ----
    {
        size_t ob = (size_t)(gb * 32 + pl) * (size_t)Mm;
#pragma unroll
        for (int g = 0; g < 8; ++g) {
            int r0 = g * 4;
            int m0 = 64 * w + (r0 >> 4) * 32 + 8 * ((r0 >> 2) & 3) + 4 * h;
            if (m0 < Mm) {
                float4 v = make_float4(a_[r0], a_[r0 + 1], a_[r0 + 2], a_[r0 + 3]);
                *(float4*)&attn_out[ob + m0] = v;
            }
        }
    }

    // ---- build + exchange GEMM2 B-fragments (attn f16, k=m) ----
    uint4 bloc[4];
#pragma unroll
    for (int t = 0; t < 2; ++t) {
        unsigned p0 = pkr(a_[16 * t + 0], a_[16 * t + 1]);
        unsigned p1 = pkr(a_[16 * t + 2], a_[16 * t + 3]);
        unsigned p2 = pkr(a_[16 * t + 4], a_[16 * t + 5]);
        unsigned p3 = pkr(a_[16 * t + 6], a_[16 * t + 7]);
        unsigned p4 = pkr(a_[16 * t + 8], a_[16 * t + 9]);
        unsigned p5 = pkr(a_[16 * t + 10], a_[16 * t + 11]);
        unsigned p6 = pkr(a_[16 * t + 12], a_[16 * t + 13]);
        unsigned p7 = pkr(a_[16 * t + 14], a_[16 * t + 15]);
        unsigned s0 = __shfl_xor(p0, 32), s1 = __shfl_xor(p1, 32);
        unsigned s2 = __shfl_xor(p2, 32), s3 = __shfl_xor(p3, 32);
        unsigned s4 = __shfl_xor(p4, 32), s5 = __shfl_xor(p5, 32);
        unsigned s6 = __shfl_xor(p6, 32), s7 = __shfl_xor(p7, 32);
        bloc[2 * t]     = h ? make_uint4(s2, s3, p2, p3) : make_uint4(p0, p1, s0, s1);
        bloc[2 * t + 1] = h ? make_uint4(s6, s7, p6, p7) : make_uint4(p4, p5, s4, s5);
    }
    uint4* bx = (uint4*)&sx[0][0][0];  // safe: all score reads done (asum barrier)
#pragma unroll
    for (int i = 0; i < 4; ++i) bx[(4 * w + i) * 64 + l] = bloc[i];
    __syncthreads();
    uint4 bfr[8];
#pragma unroll
    for (int i = 0; i < 4; ++i) {
        bfr[4 * w + i] = bloc[i];
        bfr[4 * (1 - w) + i] = bx[(4 * (1 - w) + i) * 64 + l];
    }

    // ---------------- GEMM2 (c-half): z_hat = memT . attn ----------------
    const uint4* mu4 = (const uint4*)muF;
    float* zo = zhat + (size_t)b * Cc * Nn + pxb + pl;
    const int ct0 = w * 12;
#pragma unroll 1
    for (int cti = 0; cti < 12; cti += 2) {
        int ct = ct0 + cti;
        f32x16 a2 = zero16(), a3 = zero16();
#pragma unroll
        for (int ms = 0; ms < 8; ++ms) {
            U4H8 A0, A1, Bf;
            A0.u = mu4[(ct * 8 + ms) * 64 + l];
            A1.u = mu4[((ct + 1) * 8 + ms) * 64 + l];
            Bf.u = bfr[ms];
            a2 = __builtin_amdgcn_mfma_f32_32x32x16_f16(A0.h, Bf.h, a2, 0, 0, 0);
            a3 = __builtin_amdgcn_mfma_f32_32x32x16_f16(A1.h, Bf.h, a3, 0, 0, 0);
        }
#pragma unroll
        for (int r = 0; r < 16; ++r) {
            int cl = (r & 3) + 8 * (r >> 2) + 4 * h;
            zo[(size_t)(ct * 32 + cl) * Nn] = a2[r];
            zo[(size_t)(ct * 32 + 32 + cl) * Nn] = a3[r];
        }
    }
}

extern "C" void kernel_launch(void* const* d_in, const int* in_sizes, int n_in,
                              void* d_out, int out_size, void* d_ws, size_t ws_size,
                              hipStream_t stream) {
    const float* z = (const float*)d_in[0];
    const float* mem = (const float*)d_in[1];
    float* out = (float*)d_out;
    float* zhat = out;                          // 64*768*1024
    float* attn = out + (size_t)Bn * Cc * Nn;   // 64*1024*100
    _Float16* mhiF = (_Float16*)d_ws;           // 192 KB
    _Float16* mloF = mhiF + 48 * 4 * 64 * 8;    // 192 KB
    _Float16* muF = mloF + 48 * 4 * 64 * 8;     // 192 KB

    prep_kernel<<<128, 256, 0, stream>>>(mem, mhiF, mloF, muF);
    fused_mem_kernel<<<2048, 128, 0, stream>>>(z, mhiF, mloF, muF, zhat, attn);
}

// Round 7
// 193.984 us; speedup vs baseline: 1.9710x; 1.1263x over previous
//
#include <hip/hip_runtime.h>

#define EPSF 1e-8f

typedef __fp16   h2v   __attribute__((ext_vector_type(2)));
typedef _Float16 half8 __attribute__((ext_vector_type(8)));
typedef float    f32x16 __attribute__((ext_vector_type(16)));

constexpr int Bn = 64, Cc = 768, Nn = 1024, Mm = 100;

__device__ inline f32x16 zero16() {
    f32x16 z;
#pragma unroll
    for (int i = 0; i < 16; ++i) z[i] = 0.f;
    return z;
}

union U4H8 { uint4 u; half8 h; h2v p[4]; };

__device__ inline unsigned pkr(float a, float b) {
    union { h2v p; unsigned u; } cv;
    cv.p = __builtin_amdgcn_cvt_pkrtz(a, b);
    return cv.u;
}

// Fragment-major prep (unchanged).
// GEMM1 A (normalized mem, hi/lo f16):  idx = ((cs*4 + mt)*64 + hb*32 + ml)*8 + j
// GEMM2 A (raw mem, transposed):        idx = ((ct*8 + ms)*64 + hm*32 + cl)*8 + jm
__global__ __launch_bounds__(256) void prep_kernel(const float* __restrict__ mem,
                                                   _Float16* __restrict__ mhiF,
                                                   _Float16* __restrict__ mloF,
                                                   _Float16* __restrict__ muF) {
    int m = blockIdx.x, t = threadIdx.x;
    float inv = 0.f;
    if (m < Mm) {
        float ss = 0.f;
        for (int c = t; c < Cc; c += 256) { float v = mem[m * Cc + c]; ss += v * v; }
        __shared__ float red[256];
        red[t] = ss; __syncthreads();
        for (int s = 128; s > 0; s >>= 1) { if (t < s) red[t] += red[t + s]; __syncthreads(); }
        inv = 1.f / fmaxf(sqrtf(red[0]), 1e-12f);
    }
    for (int c = t; c < Cc; c += 256) {
        float v = (m < Mm) ? mem[m * Cc + c] : 0.f;
        float nv = v * inv;
        _Float16 hh = (_Float16)nv;
        _Float16 ll = (_Float16)(nv - (float)hh);
        int cs = c >> 4, hb = (c >> 3) & 1, j = c & 7, mt = m >> 5, ml = m & 31;
        size_t idx = ((size_t)(cs * 4 + mt) * 64 + hb * 32 + ml) * 8 + j;
        mhiF[idx] = hh;
        mloF[idx] = ll;
        int ct = c >> 5, cl = c & 31, ms = m >> 4, hm = (m >> 3) & 1, jm = m & 7;
        size_t idx2 = ((size_t)(ct * 8 + ms) * 64 + hm * 32 + cl) * 8 + jm;
        muF[idx2] = (_Float16)v;
    }
}

// Block = 4 waves sharing one 32-px group. Wave w owns m-tile w (full K) in
// GEMM1 and c-quarter w in GEMM2. 2048 blocks x 256 thr = 8192 waves.
// Live set ~90 regs (acc only 16 AGPR) -> (256,4) cap 128, no spill.
__global__ __launch_bounds__(256, 4) void fused_mem_kernel(
    const float* __restrict__ z, const _Float16* __restrict__ mhiF,
    const _Float16* __restrict__ mloF, const _Float16* __restrict__ muF,
    float* __restrict__ zhat, float* __restrict__ attn_out) {
    __shared__ uint4 bx[8 * 64];      // 8 KB: GEMM2 B-fragment exchange
    __shared__ float r2x[3][4][32];   // 1.5 KB: max / sum / asum exchanges

    const int tid = threadIdx.x;
    const int w = tid >> 6;           // wave: m-tile owner (GEMM1), c-quarter (GEMM2)
    const int l = tid & 63;
    const int gb = blockIdx.x;        // one 32-px group per block
    const int b = gb >> 5;
    const int pxb = (gb & 31) * 32;
    const int pl = l & 31;
    const int h = l >> 5;
    const float* zr = z + (size_t)b * Cc * Nn + pxb + pl + (size_t)h * 8 * Nn;
    const uint4* mh4 = (const uint4*)mhiF;
    const uint4* ml4 = (const uint4*)mloF;

    // ---------------- GEMM1: scoresT tile w, full K, depth-2 pipeline ----------------
    f32x16 acc = zero16();
    float ss = 0.f;
    float zA[8], zB[8];
    uint4 fhA, flA, fhB, flB;
#pragma unroll
    for (int j = 0; j < 8; ++j) zA[j] = zr[(size_t)j * Nn];
    fhA = mh4[(0 * 4 + w) * 64 + l]; flA = ml4[(0 * 4 + w) * 64 + l];
#pragma unroll
    for (int j = 0; j < 8; ++j) zB[j] = zr[(size_t)(16 + j) * Nn];
    fhB = mh4[(1 * 4 + w) * 64 + l]; flB = ml4[(1 * 4 + w) * 64 + l];

#pragma unroll 2
    for (int cs = 0; cs < 48; cs += 2) {
        {   // even step: consume A (loaded 2 steps ago), reload A <- cs+2
            U4H8 zh, zl8, ah, al;
            ah.u = fhA; al.u = flA;
#pragma unroll
            for (int t = 0; t < 4; ++t) {
                float u = zA[2 * t], v = zA[2 * t + 1];
                h2v p = __builtin_amdgcn_cvt_pkrtz(u, v);
                zh.p[t] = p;
                zl8.p[t] = __builtin_amdgcn_cvt_pkrtz(u - (float)p.x, v - (float)p.y);
                ss += u * u + v * v;
            }
            if (cs + 2 < 48) {
#pragma unroll
                for (int j = 0; j < 8; ++j) zA[j] = zr[(size_t)((cs + 2) * 16 + j) * Nn];
                fhA = mh4[((cs + 2) * 4 + w) * 64 + l];
                flA = ml4[((cs + 2) * 4 + w) * 64 + l];
            }
            acc = __builtin_amdgcn_mfma_f32_32x32x16_f16(ah.h, zh.h, acc, 0, 0, 0);
            acc = __builtin_amdgcn_mfma_f32_32x32x16_f16(al.h, zh.h, acc, 0, 0, 0);
            acc = __builtin_amdgcn_mfma_f32_32x32x16_f16(ah.h, zl8.h, acc, 0, 0, 0);
        }
        {   // odd step: consume B, reload B <- cs+3
            U4H8 zh, zl8, ah, al;
            ah.u = fhB; al.u = flB;
#pragma unroll
            for (int t = 0; t < 4; ++t) {
                float u = zB[2 * t], v = zB[2 * t + 1];
                h2v p = __builtin_amdgcn_cvt_pkrtz(u, v);
                zh.p[t] = p;
                zl8.p[t] = __builtin_amdgcn_cvt_pkrtz(u - (float)p.x, v - (float)p.y);
                ss += u * u + v * v;
            }
            if (cs + 3 < 48) {
#pragma unroll
                for (int j = 0; j < 8; ++j) zB[j] = zr[(size_t)((cs + 3) * 16 + j) * Nn];
                fhB = mh4[((cs + 3) * 4 + w) * 64 + l];
                flB = ml4[((cs + 3) * 4 + w) * 64 + l];
            }
            acc = __builtin_amdgcn_mfma_f32_32x32x16_f16(ah.h, zh.h, acc, 0, 0, 0);
            acc = __builtin_amdgcn_mfma_f32_32x32x16_f16(al.h, zh.h, acc, 0, 0, 0);
            acc = __builtin_amdgcn_mfma_f32_32x32x16_f16(ah.h, zl8.h, acc, 0, 0, 0);
        }
    }

    // ---------------- softmax + hard shrinkage (wave owns m = 32w..32w+31) ----------------
    ss += __shfl_xor(ss, 32);
    float invn = 1.f / fmaxf(sqrtf(ss), 1e-12f);

    float a_[16];
#pragma unroll
    for (int rr = 0; rr < 16; ++rr) {
        float v = acc[rr] * invn;
        if (w == 3 && !(h == 0 && rr < 4)) v = -3.0e38f;  // m >= 100 pad
        a_[rr] = v;
    }
    float mx = -3.0e38f;
#pragma unroll
    for (int rr = 0; rr < 16; ++rr) mx = fmaxf(mx, a_[rr]);
    mx = fmaxf(mx, __shfl_xor(mx, 32));
    if (h == 0) r2x[0][w][pl] = mx;
    __syncthreads();
    mx = fmaxf(fmaxf(r2x[0][0][pl], r2x[0][1][pl]), fmaxf(r2x[0][2][pl], r2x[0][3][pl]));

    float sum = 0.f;
#pragma unroll
    for (int rr = 0; rr < 16; ++rr) { float e = expf(a_[rr] - mx); a_[rr] = e; sum += e; }
    sum += __shfl_xor(sum, 32);
    if (h == 0) r2x[1][w][pl] = sum;
    __syncthreads();
    float itot = 1.f / (r2x[1][0][pl] + r2x[1][1][pl] + r2x[1][2][pl] + r2x[1][3][pl]);

    float asum = 0.f;
#pragma unroll
    for (int rr = 0; rr < 16; ++rr) {
        float wgt = a_[rr] * itot;
        float d = wgt - 0.01f;
        float aa = (d > 0.f) ? (d * wgt) / (d + EPSF) : 0.f;
        a_[rr] = aa; asum += aa;
    }
    asum += __shfl_xor(asum, 32);
    if (h == 0) r2x[2][w][pl] = asum;
    __syncthreads();
    float ia = 1.f / (r2x[2][0][pl] + r2x[2][1][pl] + r2x[2][2][pl] + r2x[2][3][pl] + EPSF);
#pragma unroll
    for (int rr = 0; rr < 16; ++rr) a_[rr] *= ia;

    // ---- store attn (own 32-m range) ----
    {
        size_t ob = (size_t)(gb * 32 + pl) * (size_t)Mm;
#pragma unroll
        for (int q = 0; q < 4; ++q) {
            int m0 = 32 * w + 8 * q + 4 * h;
            if (m0 < Mm) {
                float4 v = make_float4(a_[4 * q], a_[4 * q + 1], a_[4 * q + 2], a_[4 * q + 3]);
                *(float4*)&attn_out[ob + m0] = v;
            }
        }
    }

    // ---- build + exchange GEMM2 B-fragments (attn f16, k=m) ----
    {
        unsigned p0 = pkr(a_[0], a_[1]),   p1 = pkr(a_[2], a_[3]);
        unsigned p2 = pkr(a_[4], a_[5]),   p3 = pkr(a_[6], a_[7]);
        unsigned p4 = pkr(a_[8], a_[9]),   p5 = pkr(a_[10], a_[11]);
        unsigned p6 = pkr(a_[12], a_[13]), p7 = pkr(a_[14], a_[15]);
        unsigned s0 = __shfl_xor(p0, 32), s1 = __shfl_xor(p1, 32);
        unsigned s2 = __shfl_xor(p2, 32), s3 = __shfl_xor(p3, 32);
        unsigned s4 = __shfl_xor(p4, 32), s5 = __shfl_xor(p5, 32);
        unsigned s6 = __shfl_xor(p6, 32), s7 = __shfl_xor(p7, 32);
        uint4 b0 = h ? make_uint4(s2, s3, p2, p3) : make_uint4(p0, p1, s0, s1);
        uint4 b1 = h ? make_uint4(s6, s7, p6, p7) : make_uint4(p4, p5, s4, s5);
        bx[(2 * w + 0) * 64 + l] = b0;
        bx[(2 * w + 1) * 64 + l] = b1;
    }
    __syncthreads();
    uint4 bfr[8];
#pragma unroll
    for (int i = 0; i < 8; ++i) bfr[i] = bx[i * 64 + l];

    // ---------------- GEMM2 (c-quarter): z_hat = memT . attn ----------------
    const uint4* mu4 = (const uint4*)muF;
    float* zo = zhat + (size_t)b * Cc * Nn + pxb + pl;
    const int ct0 = w * 6;
#pragma unroll 1
    for (int cti = 0; cti < 6; cti += 2) {
        int ct = ct0 + cti;
        f32x16 a2 = zero16(), a3 = zero16();
#pragma unroll
        for (int ms = 0; ms < 8; ++ms) {
            U4H8 A0, A1, Bf;
            A0.u = mu4[(ct * 8 + ms) * 64 + l];
            A1.u = mu4[((ct + 1) * 8 + ms) * 64 + l];
            Bf.u = bfr[ms];
            a2 = __builtin_amdgcn_mfma_f32_32x32x16_f16(A0.h, Bf.h, a2, 0, 0, 0);
            a3 = __builtin_amdgcn_mfma_f32_32x32x16_f16(A1.h, Bf.h, a3, 0, 0, 0);
        }
#pragma unroll
        for (int r = 0; r < 16; ++r) {
            int cl = (r & 3) + 8 * (r >> 2) + 4 * h;
            zo[(size_t)(ct * 32 + cl) * Nn] = a2[r];
            zo[(size_t)(ct * 32 + 32 + cl) * Nn] = a3[r];
        }
    }
}

extern "C" void kernel_launch(void* const* d_in, const int* in_sizes, int n_in,
                              void* d_out, int out_size, void* d_ws, size_t ws_size,
                              hipStream_t stream) {
    const float* z = (const float*)d_in[0];
    const float* mem = (const float*)d_in[1];
    float* out = (float*)d_out;
    float* zhat = out;                          // 64*768*1024
    float* attn = out + (size_t)Bn * Cc * Nn;   // 64*1024*100
    _Float16* mhiF = (_Float16*)d_ws;           // 192 KB
    _Float16* mloF = mhiF + 48 * 4 * 64 * 8;    // 192 KB
    _Float16* muF = mloF + 48 * 4 * 64 * 8;     // 192 KB

    prep_kernel<<<128, 256, 0, stream>>>(mem, mhiF, mloF, muF);
    fused_mem_kernel<<<2048, 256, 0, stream>>>(z, mhiF, mloF, muF, zhat, attn);
}

// Round 8
// 134.091 us; speedup vs baseline: 2.8513x; 1.4467x over previous
//
#include <hip/hip_runtime.h>

#define EPSF 1e-8f

typedef __fp16   h2v   __attribute__((ext_vector_type(2)));
typedef _Float16 half8 __attribute__((ext_vector_type(8)));
typedef float    f32x16 __attribute__((ext_vector_type(16)));

constexpr int Bn = 64, Cc = 768, Nn = 1024, Mm = 100;

__device__ inline f32x16 zero16() {
    f32x16 z;
#pragma unroll
    for (int i = 0; i < 16; ++i) z[i] = 0.f;
    return z;
}

union U4H8 { uint4 u; half8 h; h2v p[4]; };

__device__ inline unsigned pkr(float a, float b) {
    union { h2v p; unsigned u; } cv;
    cv.p = __builtin_amdgcn_cvt_pkrtz(a, b);
    return cv.u;
}

// Fragment-major prep (unchanged layouts).
// GEMM1 A (normalized mem, hi/lo f16):  idx = ((cs*4 + mt)*64 + hb*32 + ml)*8 + j
// GEMM2 A (raw mem, transposed):        idx = ((ct*8 + ms)*64 + hm*32 + cl)*8 + jm
__global__ __launch_bounds__(256) void prep_kernel(const float* __restrict__ mem,
                                                   _Float16* __restrict__ mhiF,
                                                   _Float16* __restrict__ mloF,
                                                   _Float16* __restrict__ muF) {
    int m = blockIdx.x, t = threadIdx.x;
    float inv = 0.f;
    if (m < Mm) {
        float ss = 0.f;
        for (int c = t; c < Cc; c += 256) { float v = mem[m * Cc + c]; ss += v * v; }
        __shared__ float red[256];
        red[t] = ss; __syncthreads();
        for (int s = 128; s > 0; s >>= 1) { if (t < s) red[t] += red[t + s]; __syncthreads(); }
        inv = 1.f / fmaxf(sqrtf(red[0]), 1e-12f);
    }
    for (int c = t; c < Cc; c += 256) {
        float v = (m < Mm) ? mem[m * Cc + c] : 0.f;
        float nv = v * inv;
        _Float16 hh = (_Float16)nv;
        _Float16 ll = (_Float16)(nv - (float)hh);
        int cs = c >> 4, hb = (c >> 3) & 1, j = c & 7, mt = m >> 5, ml = m & 31;
        size_t idx = ((size_t)(cs * 4 + mt) * 64 + hb * 32 + ml) * 8 + j;
        mhiF[idx] = hh;
        mloF[idx] = ll;
        int ct = c >> 5, cl = c & 31, ms = m >> 4, hm = (m >> 3) & 1, jm = m & 7;
        size_t idx2 = ((size_t)(ct * 8 + ms) * 64 + hm * 32 + cl) * 8 + jm;
        muF[idx2] = (_Float16)v;
    }
}

// Kernel A: one wave per 32-px group (2048 waves). All 4 m-tiles per wave
// (z loaded/converted ONCE per group). Depth-4 z prefetch + depth-2 frag
// prefetch to cover ~900cy latency with MLP. No LDS, no barriers.
__global__ __launch_bounds__(256, 2) void score_kernel(
    const float* __restrict__ z, const _Float16* __restrict__ mhiF,
    const _Float16* __restrict__ mloF, float* __restrict__ attn_out) {
    const int tid = threadIdx.x;
    const int l = tid & 63;
    const int wid = (blockIdx.x << 2) | (tid >> 6);  // 0..2047
    const int b = wid >> 5;
    const int pxb = (wid & 31) * 32;
    const int pl = l & 31;
    const int h = l >> 5;
    const float* zr = z + (size_t)b * Cc * Nn + pxb + pl + (size_t)h * 8 * Nn;
    const uint4* mh4 = (const uint4*)mhiF;
    const uint4* ml4 = (const uint4*)mloF;

    f32x16 acc[4] = {zero16(), zero16(), zero16(), zero16()};
    float ss = 0.f;
    float zbuf[4][8];
    uint4 fh[2][4], fl[2][4];
#pragma unroll
    for (int d = 0; d < 4; ++d)
#pragma unroll
        for (int j = 0; j < 8; ++j) zbuf[d][j] = zr[(size_t)(d * 16 + j) * Nn];
#pragma unroll
    for (int d = 0; d < 2; ++d)
#pragma unroll
        for (int mt = 0; mt < 4; ++mt) {
            fh[d][mt] = mh4[(d * 4 + mt) * 64 + l];
            fl[d][mt] = ml4[(d * 4 + mt) * 64 + l];
        }

#pragma unroll 4
    for (int cs = 0; cs < 48; ++cs) {
        const int sl = cs & 3;
        const int fb = cs & 1;
        U4H8 zh, zl8;
#pragma unroll
        for (int t = 0; t < 4; ++t) {
            float u = zbuf[sl][2 * t], v = zbuf[sl][2 * t + 1];
            h2v p = __builtin_amdgcn_cvt_pkrtz(u, v);
            zh.p[t] = p;
            zl8.p[t] = __builtin_amdgcn_cvt_pkrtz(u - (float)p.x, v - (float)p.y);
            ss += u * u + v * v;
        }
        if (cs + 4 < 48) {  // z prefetch, 4 steps ahead
#pragma unroll
            for (int j = 0; j < 8; ++j)
                zbuf[sl][j] = zr[(size_t)((cs + 4) * 16 + j) * Nn];
        }
        U4H8 ah, al;
#pragma unroll
        for (int mt = 0; mt < 4; ++mt) {
            ah.u = fh[fb][mt]; al.u = fl[fb][mt];
            acc[mt] = __builtin_amdgcn_mfma_f32_32x32x16_f16(ah.h, zh.h, acc[mt], 0, 0, 0);
            acc[mt] = __builtin_amdgcn_mfma_f32_32x32x16_f16(al.h, zh.h, acc[mt], 0, 0, 0);
            acc[mt] = __builtin_amdgcn_mfma_f32_32x32x16_f16(ah.h, zl8.h, acc[mt], 0, 0, 0);
        }
        if (cs + 2 < 48) {  // fragment prefetch, 2 steps ahead
#pragma unroll
            for (int mt = 0; mt < 4; ++mt) {
                fh[fb][mt] = mh4[((cs + 2) * 4 + mt) * 64 + l];
                fl[fb][mt] = ml4[((cs + 2) * 4 + mt) * 64 + l];
            }
        }
    }

    // ---------------- in-register softmax + hard shrinkage ----------------
    ss += __shfl_xor(ss, 32);
    float invn = 1.f / fmaxf(sqrtf(ss), 1e-12f);

    float a_[64];
#pragma unroll
    for (int r = 0; r < 64; ++r) {
        int mt = r >> 4, rr = r & 15;
        float v = acc[mt][rr] * invn;
        if (r >= 52) v = -3.0e38f;
        else if (r >= 48) v = (h == 0) ? v : -3.0e38f;  // tile3: only m=96..99 valid
        a_[r] = v;
    }
    float mx = -3.0e38f;
#pragma unroll
    for (int r = 0; r < 52; ++r) mx = fmaxf(mx, a_[r]);
    mx = fmaxf(mx, __shfl_xor(mx, 32));

    float sum = 0.f;
#pragma unroll
    for (int r = 0; r < 52; ++r) { float e = expf(a_[r] - mx); a_[r] = e; sum += e; }
    sum += __shfl_xor(sum, 32);
    float itot = 1.f / sum;

    float asum = 0.f;
#pragma unroll
    for (int r = 0; r < 52; ++r) {
        float w = a_[r] * itot;
        float d = w - 0.01f;
        float aa = (d > 0.f) ? (d * w) / (d + EPSF) : 0.f;
        a_[r] = aa; asum += aa;
    }
    asum += __shfl_xor(asum, 32);
    float ia = 1.f / (asum + EPSF);
#pragma unroll
    for (int r = 0; r < 52; ++r) a_[r] *= ia;

    // ---- store attn ----
    {
        size_t ob = (size_t)(wid * 32 + pl) * (size_t)Mm;
#pragma unroll
        for (int g = 0; g < 13; ++g) {
            int r0 = g * 4;
            int m0 = (r0 >> 4) * 32 + 8 * ((r0 >> 2) & 3) + 4 * h;
            if (g < 12 || h == 0) {
                float4 v = make_float4(a_[r0], a_[r0 + 1], a_[r0 + 2], a_[r0 + 3]);
                *(float4*)&attn_out[ob + m0] = v;
            }
        }
    }
}

// Kernel B: z_hat = attn @ memory. Block = 4 waves on one 32-px group; wave w
// owns c-quarter w. B-fragments rebuilt from attn_out (fp32, L2/L3-hot).
// 2048 blocks x 4 waves = 8192 waves; store-BW-bound.
__global__ __launch_bounds__(256, 4) void recon_kernel(
    const _Float16* __restrict__ muF, const float* __restrict__ attn_out,
    float* __restrict__ zhat) {
    const int tid = threadIdx.x;
    const int w = tid >> 6;
    const int l = tid & 63;
    const int gb = blockIdx.x;
    const int b = gb >> 5;
    const int pxb = (gb & 31) * 32;
    const int pl = l & 31;
    const int h = l >> 5;

    // rebuild B-fragments: bfr[ms] holds attn[m = ms*16 + h*8 + j] as f16
    const float* ap = attn_out + (size_t)(gb * 32 + pl) * (size_t)Mm;
    uint4 bfr[8];
#pragma unroll
    for (int ms = 0; ms < 6; ++ms) {
        float4 fa = *(const float4*)&ap[ms * 16 + h * 8];
        float4 fb = *(const float4*)&ap[ms * 16 + h * 8 + 4];
        bfr[ms] = make_uint4(pkr(fa.x, fa.y), pkr(fa.z, fa.w),
                             pkr(fb.x, fb.y), pkr(fb.z, fb.w));
    }
    {
        float4 fa = (h == 0) ? *(const float4*)&ap[96] : make_float4(0.f, 0.f, 0.f, 0.f);
        bfr[6] = make_uint4(pkr(fa.x, fa.y), pkr(fa.z, fa.w), 0u, 0u);
        bfr[7] = make_uint4(0u, 0u, 0u, 0u);
    }

    const uint4* mu4 = (const uint4*)muF;
    float* zo = zhat + (size_t)b * Cc * Nn + pxb + pl;
    const int ct0 = w * 6;
#pragma unroll 1
    for (int cti = 0; cti < 6; cti += 2) {
        int ct = ct0 + cti;
        f32x16 a2 = zero16(), a3 = zero16();
#pragma unroll
        for (int ms = 0; ms < 7; ++ms) {  // ms=7 has B==0, skipped
            U4H8 A0, A1, Bf;
            A0.u = mu4[(ct * 8 + ms) * 64 + l];
            A1.u = mu4[((ct + 1) * 8 + ms) * 64 + l];
            Bf.u = bfr[ms];
            a2 = __builtin_amdgcn_mfma_f32_32x32x16_f16(A0.h, Bf.h, a2, 0, 0, 0);
            a3 = __builtin_amdgcn_mfma_f32_32x32x16_f16(A1.h, Bf.h, a3, 0, 0, 0);
        }
#pragma unroll
        for (int r = 0; r < 16; ++r) {
            int cl = (r & 3) + 8 * (r >> 2) + 4 * h;
            zo[(size_t)(ct * 32 + cl) * Nn] = a2[r];
            zo[(size_t)(ct * 32 + 32 + cl) * Nn] = a3[r];
        }
    }
}

extern "C" void kernel_launch(void* const* d_in, const int* in_sizes, int n_in,
                              void* d_out, int out_size, void* d_ws, size_t ws_size,
                              hipStream_t stream) {
    const float* z = (const float*)d_in[0];
    const float* mem = (const float*)d_in[1];
    float* out = (float*)d_out;
    float* zhat = out;                          // 64*768*1024
    float* attn = out + (size_t)Bn * Cc * Nn;   // 64*1024*100
    _Float16* mhiF = (_Float16*)d_ws;           // 192 KB
    _Float16* mloF = mhiF + 48 * 4 * 64 * 8;    // 192 KB
    _Float16* muF = mloF + 48 * 4 * 64 * 8;     // 192 KB

    prep_kernel<<<128, 256, 0, stream>>>(mem, mhiF, mloF, muF);
    score_kernel<<<512, 256, 0, stream>>>(z, mhiF, mloF, attn);
    recon_kernel<<<2048, 256, 0, stream>>>(muF, attn, zhat);
}

// Round 9
// 123.800 us; speedup vs baseline: 3.0883x; 1.0831x over previous
//
#include <hip/hip_runtime.h>

#define EPSF 1e-8f

typedef __fp16   h2v   __attribute__((ext_vector_type(2)));
typedef _Float16 half8 __attribute__((ext_vector_type(8)));
typedef float    f32x16 __attribute__((ext_vector_type(16)));

constexpr int Bn = 64, Cc = 768, Nn = 1024, Mm = 100;

__device__ inline f32x16 zero16() {
    f32x16 z;
#pragma unroll
    for (int i = 0; i < 16; ++i) z[i] = 0.f;
    return z;
}

union U4H8 { uint4 u; half8 h; h2v p[4]; };

__device__ inline unsigned pkr(float a, float b) {
    union { h2v p; unsigned u; } cv;
    cv.p = __builtin_amdgcn_cvt_pkrtz(a, b);
    return cv.u;
}

// Fragment-major prep (unchanged layouts).
// GEMM1 A (normalized mem, hi/lo f16):  idx = ((cs*4 + mt)*64 + hb*32 + ml)*8 + j
// GEMM2 A (raw mem, transposed):        idx = ((ct*8 + ms)*64 + hm*32 + cl)*8 + jm
__global__ __launch_bounds__(256) void prep_kernel(const float* __restrict__ mem,
                                                   _Float16* __restrict__ mhiF,
                                                   _Float16* __restrict__ mloF,
                                                   _Float16* __restrict__ muF) {
    int m = blockIdx.x, t = threadIdx.x;
    float inv = 0.f;
    if (m < Mm) {
        float ss = 0.f;
        for (int c = t; c < Cc; c += 256) { float v = mem[m * Cc + c]; ss += v * v; }
        __shared__ float red[256];
        red[t] = ss; __syncthreads();
        for (int s = 128; s > 0; s >>= 1) { if (t < s) red[t] += red[t + s]; __syncthreads(); }
        inv = 1.f / fmaxf(sqrtf(red[0]), 1e-12f);
    }
    for (int c = t; c < Cc; c += 256) {
        float v = (m < Mm) ? mem[m * Cc + c] : 0.f;
        float nv = v * inv;
        _Float16 hh = (_Float16)nv;
        _Float16 ll = (_Float16)(nv - (float)hh);
        int cs = c >> 4, hb = (c >> 3) & 1, j = c & 7, mt = m >> 5, ml = m & 31;
        size_t idx = ((size_t)(cs * 4 + mt) * 64 + hb * 32 + ml) * 8 + j;
        mhiF[idx] = hh;
        mloF[idx] = ll;
        int ct = c >> 5, cl = c & 31, ms = m >> 4, hm = (m >> 3) & 1, jm = m & 7;
        size_t idx2 = ((size_t)(ct * 8 + ms) * 64 + hm * 32 + cl) * 8 + jm;
        muF[idx2] = (_Float16)v;
    }
}

// Kernel A: one wave per 32-px group (2048 waves). All 4 m-tiles per wave.
// Depth-6 nontemporal z prefetch (don't thrash L2 where frags live) +
// depth-2 frag prefetch. No LDS, no barriers.
__global__ __launch_bounds__(256, 2) void score_kernel(
    const float* __restrict__ z, const _Float16* __restrict__ mhiF,
    const _Float16* __restrict__ mloF, float* __restrict__ attn_out) {
    const int tid = threadIdx.x;
    const int l = tid & 63;
    const int wid = (blockIdx.x << 2) | (tid >> 6);  // 0..2047
    const int b = wid >> 5;
    const int pxb = (wid & 31) * 32;
    const int pl = l & 31;
    const int h = l >> 5;
    const float* zr = z + (size_t)b * Cc * Nn + pxb + pl + (size_t)h * 8 * Nn;
    const uint4* mh4 = (const uint4*)mhiF;
    const uint4* ml4 = (const uint4*)mloF;

    f32x16 acc[4] = {zero16(), zero16(), zero16(), zero16()};
    float ss = 0.f;
    float zbuf[6][8];
    uint4 fh[2][4], fl[2][4];
#pragma unroll
    for (int d = 0; d < 6; ++d)
#pragma unroll
        for (int j = 0; j < 8; ++j)
            zbuf[d][j] = __builtin_nontemporal_load(&zr[(size_t)(d * 16 + j) * Nn]);
#pragma unroll
    for (int d = 0; d < 2; ++d)
#pragma unroll
        for (int mt = 0; mt < 4; ++mt) {
            fh[d][mt] = mh4[(d * 4 + mt) * 64 + l];
            fl[d][mt] = ml4[(d * 4 + mt) * 64 + l];
        }

    for (int cso = 0; cso < 8; ++cso) {
#pragma unroll
        for (int i = 0; i < 6; ++i) {
            const int cs = cso * 6 + i;   // slot = i (compile-time), fb = i&1
            const int fb = i & 1;
            U4H8 zh, zl8;
#pragma unroll
            for (int t = 0; t < 4; ++t) {
                float u = zbuf[i][2 * t], v = zbuf[i][2 * t + 1];
                h2v p = __builtin_amdgcn_cvt_pkrtz(u, v);
                zh.p[t] = p;
                zl8.p[t] = __builtin_amdgcn_cvt_pkrtz(u - (float)p.x, v - (float)p.y);
                ss += u * u + v * v;
            }
            if (cs + 6 < 48) {  // z prefetch, 6 steps ahead, nontemporal
#pragma unroll
                for (int j = 0; j < 8; ++j)
                    zbuf[i][j] = __builtin_nontemporal_load(
                        &zr[(size_t)((cs + 6) * 16 + j) * Nn]);
            }
            U4H8 ah, al;
#pragma unroll
            for (int mt = 0; mt < 4; ++mt) {
                ah.u = fh[fb][mt]; al.u = fl[fb][mt];
                acc[mt] = __builtin_amdgcn_mfma_f32_32x32x16_f16(ah.h, zh.h, acc[mt], 0, 0, 0);
                acc[mt] = __builtin_amdgcn_mfma_f32_32x32x16_f16(al.h, zh.h, acc[mt], 0, 0, 0);
                acc[mt] = __builtin_amdgcn_mfma_f32_32x32x16_f16(ah.h, zl8.h, acc[mt], 0, 0, 0);
            }
            if (cs + 2 < 48) {  // fragment prefetch, 2 steps ahead (keep L2-cached)
#pragma unroll
                for (int mt = 0; mt < 4; ++mt) {
                    fh[fb][mt] = mh4[((cs + 2) * 4 + mt) * 64 + l];
                    fl[fb][mt] = ml4[((cs + 2) * 4 + mt) * 64 + l];
                }
            }
        }
    }

    // ---------------- in-register softmax + hard shrinkage ----------------
    ss += __shfl_xor(ss, 32);
    float invn = 1.f / fmaxf(sqrtf(ss), 1e-12f);

    float a_[64];
#pragma unroll
    for (int r = 0; r < 64; ++r) {
        int mt = r >> 4, rr = r & 15;
        float v = acc[mt][rr] * invn;
        if (r >= 52) v = -3.0e38f;
        else if (r >= 48) v = (h == 0) ? v : -3.0e38f;  // tile3: only m=96..99 valid
        a_[r] = v;
    }
    float mx = -3.0e38f;
#pragma unroll
    for (int r = 0; r < 52; ++r) mx = fmaxf(mx, a_[r]);
    mx = fmaxf(mx, __shfl_xor(mx, 32));

    float sum = 0.f;
#pragma unroll
    for (int r = 0; r < 52; ++r) { float e = expf(a_[r] - mx); a_[r] = e; sum += e; }
    sum += __shfl_xor(sum, 32);
    float itot = 1.f / sum;

    float asum = 0.f;
#pragma unroll
    for (int r = 0; r < 52; ++r) {
        float w = a_[r] * itot;
        float d = w - 0.01f;
        float aa = (d > 0.f) ? (d * w) / (d + EPSF) : 0.f;
        a_[r] = aa; asum += aa;
    }
    asum += __shfl_xor(asum, 32);
    float ia = 1.f / (asum + EPSF);
#pragma unroll
    for (int r = 0; r < 52; ++r) a_[r] *= ia;

    // ---- store attn (normal stores: re-read by recon, keep cacheable) ----
    {
        size_t ob = (size_t)(wid * 32 + pl) * (size_t)Mm;
#pragma unroll
        for (int g = 0; g < 13; ++g) {
            int r0 = g * 4;
            int m0 = (r0 >> 4) * 32 + 8 * ((r0 >> 2) & 3) + 4 * h;
            if (g < 12 || h == 0) {
                float4 v = make_float4(a_[r0], a_[r0 + 1], a_[r0 + 2], a_[r0 + 3]);
                *(float4*)&attn_out[ob + m0] = v;
            }
        }
    }
}

// Kernel B: z_hat = attn @ memory. Block = 4 waves on one 32-px group; wave w
// owns c-quarter w. B-fragments rebuilt from attn_out (fp32, L2/L3-hot).
// 2048 blocks x 4 waves = 8192 waves; nontemporal z_hat stores keep muF in L2.
__global__ __launch_bounds__(256, 4) void recon_kernel(
    const _Float16* __restrict__ muF, const float* __restrict__ attn_out,
    float* __restrict__ zhat) {
    const int tid = threadIdx.x;
    const int w = tid >> 6;
    const int l = tid & 63;
    const int gb = blockIdx.x;
    const int b = gb >> 5;
    const int pxb = (gb & 31) * 32;
    const int pl = l & 31;
    const int h = l >> 5;

    // rebuild B-fragments: bfr[ms] holds attn[m = ms*16 + h*8 + j] as f16
    const float* ap = attn_out + (size_t)(gb * 32 + pl) * (size_t)Mm;
    uint4 bfr[8];
#pragma unroll
    for (int ms = 0; ms < 6; ++ms) {
        float4 fa = *(const float4*)&ap[ms * 16 + h * 8];
        float4 fb = *(const float4*)&ap[ms * 16 + h * 8 + 4];
        bfr[ms] = make_uint4(pkr(fa.x, fa.y), pkr(fa.z, fa.w),
                             pkr(fb.x, fb.y), pkr(fb.z, fb.w));
    }
    {
        float4 fa = (h == 0) ? *(const float4*)&ap[96] : make_float4(0.f, 0.f, 0.f, 0.f);
        bfr[6] = make_uint4(pkr(fa.x, fa.y), pkr(fa.z, fa.w), 0u, 0u);
        bfr[7] = make_uint4(0u, 0u, 0u, 0u);
    }

    const uint4* mu4 = (const uint4*)muF;
    float* zo = zhat + (size_t)b * Cc * Nn + pxb + pl;
    const int ct0 = w * 6;
#pragma unroll 1
    for (int cti = 0; cti < 6; cti += 2) {
        int ct = ct0 + cti;
        f32x16 a2 = zero16(), a3 = zero16();
#pragma unroll
        for (int ms = 0; ms < 7; ++ms) {  // ms=7 has B==0, skipped
            U4H8 A0, A1, Bf;
            A0.u = mu4[(ct * 8 + ms) * 64 + l];
            A1.u = mu4[((ct + 1) * 8 + ms) * 64 + l];
            Bf.u = bfr[ms];
            a2 = __builtin_amdgcn_mfma_f32_32x32x16_f16(A0.h, Bf.h, a2, 0, 0, 0);
            a3 = __builtin_amdgcn_mfma_f32_32x32x16_f16(A1.h, Bf.h, a3, 0, 0, 0);
        }
#pragma unroll
        for (int r = 0; r < 16; ++r) {
            int cl = (r & 3) + 8 * (r >> 2) + 4 * h;
            __builtin_nontemporal_store(a2[r], &zo[(size_t)(ct * 32 + cl) * Nn]);
            __builtin_nontemporal_store(a3[r], &zo[(size_t)(ct * 32 + 32 + cl) * Nn]);
        }
    }
}

extern "C" void kernel_launch(void* const* d_in, const int* in_sizes, int n_in,
                              void* d_out, int out_size, void* d_ws, size_t ws_size,
                              hipStream_t stream) {
    const float* z = (const float*)d_in[0];
    const float* mem = (const float*)d_in[1];
    float* out = (float*)d_out;
    float* zhat = out;                          // 64*768*1024
    float* attn = out + (size_t)Bn * Cc * Nn;   // 64*1024*100
    _Float16* mhiF = (_Float16*)d_ws;           // 192 KB
    _Float16* mloF = mhiF + 48 * 4 * 64 * 8;    // 192 KB
    _Float16* muF = mloF + 48 * 4 * 64 * 8;     // 192 KB

    prep_kernel<<<128, 256, 0, stream>>>(mem, mhiF, mloF, muF);
    score_kernel<<<512, 256, 0, stream>>>(z, mhiF, mloF, attn);
    recon_kernel<<<2048, 256, 0, stream>>>(muF, attn, zhat);
}